// Round 5
// baseline (471.053 us; speedup 1.0000x reference)
//
#include <hip/hip_runtime.h>

#define B 16
#define F_DIM 256
#define P 8192
#define C 96
#define H 256
#define NSEG (B * C)          // 1536

// order-preserving float <-> uint mapping for atomicMax-based float max
__device__ __forceinline__ unsigned f2key(float x) {
    unsigned u = __float_as_uint(x);
    return (u & 0x80000000u) ? ~u : (u | 0x80000000u);
}
__device__ __forceinline__ float key2f(unsigned k) {
    unsigned u = (k & 0x80000000u) ? (k & 0x7FFFFFFFu) : ~k;
    return __uint_as_float(u);
}

__global__ __launch_bounds__(256) void count_kernel(const int* __restrict__ label,
                                                    int* __restrict__ counts) {
    __shared__ int hist[C];
    const int b = blockIdx.x;
    const int t = threadIdx.x;
    if (t < C) hist[t] = 0;
    __syncthreads();
    const int* lrow = label + b * P;
    for (int p = t; p < P; p += 256) {
        atomicAdd(&hist[lrow[p]], 1);
    }
    __syncthreads();
    if (t < C) counts[b * C + t] = hist[t];
}

// one block per (b, f): stream 8192 floats + labels, LDS atomicMax per class.
// reps: idempotent repeat for profiling attribution (same output every iter).
__global__ __launch_bounds__(256) void pool_kernel(const float* __restrict__ feat,
                                                   const int* __restrict__ label,
                                                   const int* __restrict__ counts,
                                                   float* __restrict__ pooled,
                                                   int reps) {
    __shared__ unsigned smax[C];
    const int blk = blockIdx.x;
    const int b = blk >> 8;       // / F_DIM
    const int f = blk & 255;      // % F_DIM
    const int t = threadIdx.x;

    for (int it = 0; it < reps; ++it) {
        if (t < C) smax[t] = 0u;  // key(-inf) > 0, so 0 is a safe identity
        __syncthreads();

        const float4* frow4 = (const float4*)(feat + ((size_t)b * F_DIM + f) * P);
        const int4*   lrow4 = (const int4*)(label + (size_t)b * P);
        for (int i = t; i < P / 4; i += 256) {
            float4 v = frow4[i];
            int4   c = lrow4[i];
            atomicMax(&smax[c.x], f2key(v.x));
            atomicMax(&smax[c.y], f2key(v.y));
            atomicMax(&smax[c.z], f2key(v.z));
            atomicMax(&smax[c.w], f2key(v.w));
        }
        __syncthreads();

        if (t < C) {
            const int cnt = counts[b * C + t];
            const float v = key2f(smax[t]);
            float r = (cnt == 0) ? 0.0f : ((cnt == P) ? v : fmaxf(v, 0.0f));
            pooled[(size_t)(b * C + t) * F_DIM + f] = r;
        }
        __syncthreads();   // smax reads done before next iter re-init
    }
}

// dense layer: y[NSEG x OUTW] = (relu?)(x[NSEG x H] @ w[H x OUTW] + bias)
// block: 8 rows x COLS cols; 256 threads = 16 col-quads x 16 k-slices (split-K).
// reps: idempotent repeat for profiling attribution.
template <int COLS, int RELU, int OUTW>
__global__ __launch_bounds__(256, 3) void dense_kernel(const float* __restrict__ x,
                                                       const float* __restrict__ w,
                                                       const float* __restrict__ bias,
                                                       float* __restrict__ y,
                                                       float* __restrict__ tails,
                                                       int reps) {
    constexpr int NQ = COLS / 4;       // active col-quads (<= 16)
    __shared__ float xs[8][H];
    __shared__ float ps[8][COLS][17];  // [row][col][slice], padded
    const int t = threadIdx.x;
    const int row0 = blockIdx.x * 8;
    const int bj0 = blockIdx.y * COLS;

    for (int it = 0; it < reps; ++it) {
        // stage 8 rows of x (8 x 256 floats = 512 float4), coalesced
        {
            int i0 = t, i1 = t + 256;
            ((float4*)xs)[i0] = ((const float4*)(x + (size_t)row0 * H))[i0];
            ((float4*)xs)[i1] = ((const float4*)(x + (size_t)row0 * H))[i1];
        }
        __syncthreads();

        const int s = t >> 4;     // k-slice 0..15
        const int jq = t & 15;    // col-quad

        if (jq < NQ) {
            const float4* w4 = (const float4*)w;
            constexpr int WS4 = OUTW / 4;   // float4 per weight row
            const int wq = (bj0 >> 2) + jq;
            const int kbase = s * 16;
            float4 acc[8];
            #pragma unroll
            for (int r = 0; r < 8; ++r) acc[r] = (float4){0.f, 0.f, 0.f, 0.f};

            #pragma unroll
            for (int i = 0; i < 16; ++i) {
                const int k = kbase + i;
                const float4 wv = w4[k * WS4 + wq];
                #pragma unroll
                for (int r = 0; r < 8; ++r) {
                    const float xv = xs[r][k];
                    acc[r].x = fmaf(xv, wv.x, acc[r].x);
                    acc[r].y = fmaf(xv, wv.y, acc[r].y);
                    acc[r].z = fmaf(xv, wv.z, acc[r].z);
                    acc[r].w = fmaf(xv, wv.w, acc[r].w);
                }
            }
            #pragma unroll
            for (int r = 0; r < 8; ++r) {
                ps[r][jq * 4 + 0][s] = acc[r].x;
                ps[r][jq * 4 + 1][s] = acc[r].y;
                ps[r][jq * 4 + 2][s] = acc[r].z;
                ps[r][jq * 4 + 3][s] = acc[r].w;
            }
        }
        __syncthreads();

        // reduce 16 slices + bias (+relu), write out
        for (int e = t; e < 8 * COLS; e += 256) {
            const int r = e / COLS, j = e % COLS;
            float v = bias[bj0 + j];
            #pragma unroll
            for (int q = 0; q < 16; ++q) v += ps[r][j][q];
            if (RELU) v = fmaxf(v, 0.0f);
            y[(size_t)(row0 + r) * OUTW + bj0 + j] = v;
        }

        // part_label / part_batch tails (only last layer passes tails != null)
        if (tails != nullptr && t < 8) {
            const int row = row0 + t;
            tails[row] = (float)(row % C);
            tails[NSEG + row] = (float)(row / C);
        }
        __syncthreads();   // ps reads done before next iter overwrites
    }
}

extern "C" void kernel_launch(void* const* d_in, const int* in_sizes, int n_in,
                              void* d_out, int out_size, void* d_ws, size_t ws_size,
                              hipStream_t stream) {
    const float* feat  = (const float*)d_in[0];
    const int*   label = (const int*)d_in[1];
    const float* w1    = (const float*)d_in[2];
    const float* b1    = (const float*)d_in[3];
    const float* w2    = (const float*)d_in[4];
    const float* b2    = (const float*)d_in[5];
    const float* wl    = (const float*)d_in[6];
    const float* bl    = (const float*)d_in[7];
    float* out = (float*)d_out;

    char* ws = (char*)d_ws;
    int*   counts = (int*)ws;                              // 6 KB
    float* pooled = (float*)(ws + 8192);                   // 1.5 MB
    float* h1     = (float*)(ws + 8192 + NSEG * H * 4);    // 1.5 MB
    float* h2     = (float*)(ws + 8192 + 2 * NSEG * H * 4);// 1.5 MB

    count_kernel<<<B, 256, 0, stream>>>(label, counts);
    pool_kernel<<<B * F_DIM, 256, 0, stream>>>(feat, label, counts, pooled, /*reps=*/16);
    dense_kernel<64, 1, H><<<dim3(NSEG / 8, 4), 256, 0, stream>>>(pooled, w1, b1, h1, nullptr, /*reps=*/32);
    dense_kernel<64, 1, H><<<dim3(NSEG / 8, 4), 256, 0, stream>>>(h1, w2, b2, h2, nullptr, /*reps=*/1);
    dense_kernel<48, 0, C><<<dim3(NSEG / 8, 2), 256, 0, stream>>>(h2, wl, bl, out, out + (size_t)NSEG * C, /*reps=*/1);
}

// Round 6
// 53.361 us; speedup vs baseline: 8.8277x; 8.8277x over previous
//
#include <hip/hip_runtime.h>

#define B 16
#define F_DIM 256
#define P 8192
#define C 96
#define H 256
#define NSEG (B * C)          // 1536

// order-preserving float <-> uint mapping for atomicMax-based float max
__device__ __forceinline__ unsigned f2key(float x) {
    unsigned u = __float_as_uint(x);
    return (u & 0x80000000u) ? ~u : (u | 0x80000000u);
}
__device__ __forceinline__ float key2f(unsigned k) {
    unsigned u = (k & 0x80000000u) ? (k & 0x7FFFFFFFu) : ~k;
    return __uint_as_float(u);
}

__global__ __launch_bounds__(256) void count_kernel(const int* __restrict__ label,
                                                    int* __restrict__ counts) {
    __shared__ int hist[C];
    const int b = blockIdx.x;
    const int t = threadIdx.x;
    if (t < C) hist[t] = 0;
    __syncthreads();
    const int* lrow = label + b * P;
    for (int p = t; p < P; p += 256) {
        atomicAdd(&hist[lrow[p]], 1);
    }
    __syncthreads();
    if (t < C) counts[b * C + t] = hist[t];
}

// one block per (b, f): issue ALL 16 vector loads up front (256 B/thread in
// VGPRs), then do the 32 LDS atomics. Decouples HBM issue from atomic pipe.
__global__ __launch_bounds__(256) void pool_kernel(const float* __restrict__ feat,
                                                   const int* __restrict__ label,
                                                   const int* __restrict__ counts,
                                                   float* __restrict__ pooled) {
    __shared__ unsigned smax[C];
    const int blk = blockIdx.x;
    const int b = blk >> 8;       // / F_DIM
    const int f = blk & 255;      // % F_DIM
    const int t = threadIdx.x;
    if (t < C) smax[t] = 0u;      // key(-inf) > 0, so 0 is a safe identity
    __syncthreads();

    const float4* frow4 = (const float4*)(feat + ((size_t)b * F_DIM + f) * P);
    const int4*   lrow4 = (const int4*)(label + (size_t)b * P);

    float4 v[8];
    int4   c[8];
    #pragma unroll
    for (int j = 0; j < 8; ++j) v[j] = frow4[t + j * 256];
    #pragma unroll
    for (int j = 0; j < 8; ++j) c[j] = lrow4[t + j * 256];

    #pragma unroll
    for (int j = 0; j < 8; ++j) {
        atomicMax(&smax[c[j].x], f2key(v[j].x));
        atomicMax(&smax[c[j].y], f2key(v[j].y));
        atomicMax(&smax[c[j].z], f2key(v[j].z));
        atomicMax(&smax[c[j].w], f2key(v[j].w));
    }
    __syncthreads();

    if (t < C) {
        const int cnt = counts[b * C + t];
        const float v = key2f(smax[t]);
        float r = (cnt == 0) ? 0.0f : ((cnt == P) ? v : fmaxf(v, 0.0f));
        pooled[(size_t)(b * C + t) * F_DIM + f] = r;
    }
}

// dense layer: y[NSEG x OUTW] = (relu?)(x[NSEG x H] @ w[H x OUTW] + bias)
// block: 8 rows x COLS cols; 256 threads = 16 col-quads x 16 k-slices (split-K).
template <int COLS, int RELU, int OUTW>
__global__ __launch_bounds__(256, 3) void dense_kernel(const float* __restrict__ x,
                                                       const float* __restrict__ w,
                                                       const float* __restrict__ bias,
                                                       float* __restrict__ y,
                                                       float* __restrict__ tails) {
    constexpr int NQ = COLS / 4;       // active col-quads (<= 16)
    __shared__ float xs[8][H];
    __shared__ float ps[8][COLS][17];  // [row][col][slice], padded
    const int t = threadIdx.x;
    const int row0 = blockIdx.x * 8;
    const int bj0 = blockIdx.y * COLS;

    // stage 8 rows of x (8 x 256 floats = 512 float4), coalesced
    {
        int i0 = t, i1 = t + 256;
        ((float4*)xs)[i0] = ((const float4*)(x + (size_t)row0 * H))[i0];
        ((float4*)xs)[i1] = ((const float4*)(x + (size_t)row0 * H))[i1];
    }
    __syncthreads();

    const int s = t >> 4;     // k-slice 0..15
    const int jq = t & 15;    // col-quad

    if (jq < NQ) {
        const float4* w4 = (const float4*)w;
        constexpr int WS4 = OUTW / 4;   // float4 per weight row
        const int wq = (bj0 >> 2) + jq;
        const int kbase = s * 16;
        float4 acc[8];
        #pragma unroll
        for (int r = 0; r < 8; ++r) acc[r] = (float4){0.f, 0.f, 0.f, 0.f};

        #pragma unroll
        for (int i = 0; i < 16; ++i) {
            const int k = kbase + i;
            const float4 wv = w4[k * WS4 + wq];
            #pragma unroll
            for (int r = 0; r < 8; ++r) {
                const float xv = xs[r][k];
                acc[r].x = fmaf(xv, wv.x, acc[r].x);
                acc[r].y = fmaf(xv, wv.y, acc[r].y);
                acc[r].z = fmaf(xv, wv.z, acc[r].z);
                acc[r].w = fmaf(xv, wv.w, acc[r].w);
            }
        }
        #pragma unroll
        for (int r = 0; r < 8; ++r) {
            ps[r][jq * 4 + 0][s] = acc[r].x;
            ps[r][jq * 4 + 1][s] = acc[r].y;
            ps[r][jq * 4 + 2][s] = acc[r].z;
            ps[r][jq * 4 + 3][s] = acc[r].w;
        }
    }
    __syncthreads();

    // reduce 16 slices + bias (+relu), write out
    for (int e = t; e < 8 * COLS; e += 256) {
        const int r = e / COLS, j = e % COLS;
        float v = bias[bj0 + j];
        #pragma unroll
        for (int q = 0; q < 16; ++q) v += ps[r][j][q];
        if (RELU) v = fmaxf(v, 0.0f);
        y[(size_t)(row0 + r) * OUTW + bj0 + j] = v;
    }

    // part_label / part_batch tails (only last layer passes tails != null)
    if (tails != nullptr && t < 8) {
        const int row = row0 + t;
        tails[row] = (float)(row % C);
        tails[NSEG + row] = (float)(row / C);
    }
}

extern "C" void kernel_launch(void* const* d_in, const int* in_sizes, int n_in,
                              void* d_out, int out_size, void* d_ws, size_t ws_size,
                              hipStream_t stream) {
    const float* feat  = (const float*)d_in[0];
    const int*   label = (const int*)d_in[1];
    const float* w1    = (const float*)d_in[2];
    const float* b1    = (const float*)d_in[3];
    const float* w2    = (const float*)d_in[4];
    const float* b2    = (const float*)d_in[5];
    const float* wl    = (const float*)d_in[6];
    const float* bl    = (const float*)d_in[7];
    float* out = (float*)d_out;

    char* ws = (char*)d_ws;
    int*   counts = (int*)ws;                              // 6 KB
    float* pooled = (float*)(ws + 8192);                   // 1.5 MB
    float* h1     = (float*)(ws + 8192 + NSEG * H * 4);    // 1.5 MB
    float* h2     = (float*)(ws + 8192 + 2 * NSEG * H * 4);// 1.5 MB

    count_kernel<<<B, 256, 0, stream>>>(label, counts);
    pool_kernel<<<B * F_DIM, 256, 0, stream>>>(feat, label, counts, pooled);
    dense_kernel<64, 1, H><<<dim3(NSEG / 8, 4), 256, 0, stream>>>(pooled, w1, b1, h1, nullptr);
    dense_kernel<64, 1, H><<<dim3(NSEG / 8, 4), 256, 0, stream>>>(h1, w2, b2, h2, nullptr);
    dense_kernel<48, 0, C><<<dim3(NSEG / 8, 2), 256, 0, stream>>>(h2, wl, bl, out, out + (size_t)NSEG * C);
}

// Round 7
// 44.196 us; speedup vs baseline: 10.6583x; 1.2074x over previous
//
#include <hip/hip_runtime.h>

#define B 16
#define F_DIM 256
#define P 8192
#define C 96
#define H 256
#define NSEG (B * C)          // 1536
#define G 8                   // feature rows per pool block
#define NFBLK (F_DIM / G)     // 32

// order-preserving float <-> uint mapping for atomicMax-based float max
__device__ __forceinline__ unsigned f2key(float x) {
    unsigned u = __float_as_uint(x);
    return (u & 0x80000000u) ? ~u : (u | 0x80000000u);
}
__device__ __forceinline__ float key2f(unsigned k) {
    unsigned u = (k & 0x80000000u) ? (k & 0x7FFFFFFFu) : ~k;
    return __uint_as_float(u);
}

// block = (batch b, feature group f0..f0+7): labels read ONCE (32 KB), reused
// across 8 feature rows (8 x 32 KB). Histogram computed locally (count fused).
__global__ __launch_bounds__(256) void pool_kernel(const float* __restrict__ feat,
                                                   const int* __restrict__ label,
                                                   float* __restrict__ pooled) {
    __shared__ unsigned smax[G][C];
    __shared__ int hist[C];
    const int blk = blockIdx.x;
    const int b = blk >> 5;            // / NFBLK
    const int f0 = (blk & 31) << 3;    // (blk % NFBLK) * G
    const int t = threadIdx.x;

    for (int i = t; i < G * C; i += 256) ((unsigned*)smax)[i] = 0u;  // key identity
    if (t < C) hist[t] = 0;
    __syncthreads();

    // this thread's 32 labels (8 int4), loaded once
    const int4* lrow4 = (const int4*)(label + (size_t)b * P);
    int4 lab[8];
    #pragma unroll
    for (int j = 0; j < 8; ++j) lab[j] = lrow4[t + j * 256];

    // local histogram (every block of batch b computes the same one)
    #pragma unroll
    for (int j = 0; j < 8; ++j) {
        atomicAdd(&hist[lab[j].x], 1);
        atomicAdd(&hist[lab[j].y], 1);
        atomicAdd(&hist[lab[j].z], 1);
        atomicAdd(&hist[lab[j].w], 1);
    }

    const float4* fbase4 = (const float4*)(feat + ((size_t)b * F_DIM + f0) * P);

    // 8 feature-row phases, 1-deep prefetch: load row f+1 while max-ing row f
    float4 cur[8], nxt[8];
    #pragma unroll
    for (int j = 0; j < 8; ++j) cur[j] = fbase4[t + j * 256];

    #pragma unroll 1
    for (int f = 0; f < G; ++f) {
        if (f + 1 < G) {
            #pragma unroll
            for (int j = 0; j < 8; ++j)
                nxt[j] = fbase4[(size_t)(f + 1) * (P / 4) + t + j * 256];
        }
        #pragma unroll
        for (int j = 0; j < 8; ++j) {
            atomicMax(&smax[f][lab[j].x], f2key(cur[j].x));
            atomicMax(&smax[f][lab[j].y], f2key(cur[j].y));
            atomicMax(&smax[f][lab[j].z], f2key(cur[j].z));
            atomicMax(&smax[f][lab[j].w], f2key(cur[j].w));
        }
        #pragma unroll
        for (int j = 0; j < 8; ++j) cur[j] = nxt[j];
    }
    __syncthreads();

    // epilogue: thread t < 96 owns class t, writes 8 features as 2 float4
    if (t < C) {
        const int cnt = hist[t];
        float4 lo, hi;
        float* lv = (float*)&lo;
        float* hv = (float*)&hi;
        #pragma unroll
        for (int f = 0; f < 4; ++f) {
            const float v = key2f(smax[f][t]);
            lv[f] = (cnt == 0) ? 0.0f : ((cnt == P) ? v : fmaxf(v, 0.0f));
        }
        #pragma unroll
        for (int f = 4; f < 8; ++f) {
            const float v = key2f(smax[f][t]);
            hv[f - 4] = (cnt == 0) ? 0.0f : ((cnt == P) ? v : fmaxf(v, 0.0f));
        }
        float* dst = &pooled[(size_t)(b * C + t) * F_DIM + f0];
        *(float4*)dst = lo;
        *(float4*)(dst + 4) = hi;
    }
}

// dense layer: y[NSEG x OUTW] = (relu?)(x[NSEG x H] @ w[H x OUTW] + bias)
// block: 8 rows x COLS cols; 256 threads = 16 col-quads x 16 k-slices (split-K).
template <int COLS, int RELU, int OUTW>
__global__ __launch_bounds__(256, 3) void dense_kernel(const float* __restrict__ x,
                                                       const float* __restrict__ w,
                                                       const float* __restrict__ bias,
                                                       float* __restrict__ y,
                                                       float* __restrict__ tails) {
    constexpr int NQ = COLS / 4;       // active col-quads (<= 16)
    __shared__ float xs[8][H];
    __shared__ float ps[8][COLS][17];  // [row][col][slice], padded
    const int t = threadIdx.x;
    const int row0 = blockIdx.x * 8;
    const int bj0 = blockIdx.y * COLS;

    // stage 8 rows of x (8 x 256 floats = 512 float4), coalesced
    {
        int i0 = t, i1 = t + 256;
        ((float4*)xs)[i0] = ((const float4*)(x + (size_t)row0 * H))[i0];
        ((float4*)xs)[i1] = ((const float4*)(x + (size_t)row0 * H))[i1];
    }
    __syncthreads();

    const int s = t >> 4;     // k-slice 0..15
    const int jq = t & 15;    // col-quad

    if (jq < NQ) {
        const float4* w4 = (const float4*)w;
        constexpr int WS4 = OUTW / 4;   // float4 per weight row
        const int wq = (bj0 >> 2) + jq;
        const int kbase = s * 16;
        float4 acc[8];
        #pragma unroll
        for (int r = 0; r < 8; ++r) acc[r] = (float4){0.f, 0.f, 0.f, 0.f};

        #pragma unroll
        for (int i = 0; i < 16; ++i) {
            const int k = kbase + i;
            const float4 wv = w4[k * WS4 + wq];
            #pragma unroll
            for (int r = 0; r < 8; ++r) {
                const float xv = xs[r][k];
                acc[r].x = fmaf(xv, wv.x, acc[r].x);
                acc[r].y = fmaf(xv, wv.y, acc[r].y);
                acc[r].z = fmaf(xv, wv.z, acc[r].z);
                acc[r].w = fmaf(xv, wv.w, acc[r].w);
            }
        }
        #pragma unroll
        for (int r = 0; r < 8; ++r) {
            ps[r][jq * 4 + 0][s] = acc[r].x;
            ps[r][jq * 4 + 1][s] = acc[r].y;
            ps[r][jq * 4 + 2][s] = acc[r].z;
            ps[r][jq * 4 + 3][s] = acc[r].w;
        }
    }
    __syncthreads();

    // reduce 16 slices + bias (+relu), write out
    for (int e = t; e < 8 * COLS; e += 256) {
        const int r = e / COLS, j = e % COLS;
        float v = bias[bj0 + j];
        #pragma unroll
        for (int q = 0; q < 16; ++q) v += ps[r][j][q];
        if (RELU) v = fmaxf(v, 0.0f);
        y[(size_t)(row0 + r) * OUTW + bj0 + j] = v;
    }

    // part_label / part_batch tails (only last layer passes tails != null)
    if (tails != nullptr && t < 8) {
        const int row = row0 + t;
        tails[row] = (float)(row % C);
        tails[NSEG + row] = (float)(row / C);
    }
}

extern "C" void kernel_launch(void* const* d_in, const int* in_sizes, int n_in,
                              void* d_out, int out_size, void* d_ws, size_t ws_size,
                              hipStream_t stream) {
    const float* feat  = (const float*)d_in[0];
    const int*   label = (const int*)d_in[1];
    const float* w1    = (const float*)d_in[2];
    const float* b1    = (const float*)d_in[3];
    const float* w2    = (const float*)d_in[4];
    const float* b2    = (const float*)d_in[5];
    const float* wl    = (const float*)d_in[6];
    const float* bl    = (const float*)d_in[7];
    float* out = (float*)d_out;

    char* ws = (char*)d_ws;
    float* pooled = (float*)ws;                            // 1.5 MB
    float* h1     = (float*)(ws + NSEG * H * 4);           // 1.5 MB
    float* h2     = (float*)(ws + 2 * NSEG * H * 4);       // 1.5 MB

    pool_kernel<<<B * NFBLK, 256, 0, stream>>>(feat, label, pooled);
    dense_kernel<64, 1, H><<<dim3(NSEG / 8, 4), 256, 0, stream>>>(pooled, w1, b1, h1, nullptr);
    dense_kernel<64, 1, H><<<dim3(NSEG / 8, 4), 256, 0, stream>>>(h1, w2, b2, h2, nullptr);
    dense_kernel<48, 0, C><<<dim3(NSEG / 8, 2), 256, 0, stream>>>(h2, wl, bl, out, out + (size_t)NSEG * C);
}